// Round 1
// 182.627 us; speedup vs baseline: 1.0149x; 1.0149x over previous
//
#include <hip/hip_runtime.h>

// VisualRetina: strided 32x32 downsample -> Z-order -> per-16-chunk cubic LS fit
// -> [4 coeffs + sigma] channel-mean.
//
// v2: cooperative-gather restructure. One block per (batch, 8-row group of the
// 32x32 grid): 256 threads stage the 3ch x 8row x 32col strided grid points
// into LDS (3 independent loads/thread), then 48 threads fit the 16 (c,chunk)
// pairs covered by those rows, then 16 threads channel-average and store.
// Grid = 1024 blocks x 256 thr = 16 waves/CU (vs 1 wave/CU before) -> the
// scattered-load latency is hidden by TLP instead of serializing per-wave.
//
// Z-order decode: chunk n covers a 4x4 block at (4*yh(n), 4*xh(n)); element t
// is (dy(t), dx(t)). Grid (y,x) -> pixel (7y, 7x) since 224//32*arange = 7*.
//
// LS solve decouples by basis parity (t symmetric around 0):
//   [S6 S4; S4 S2][a3;a1] = [St3y; Sty],  [S4 S2; S2 16][a2;a0] = [St2y; Sy]
// Residual SS = Sy^2 - a^T (T^T y)  (exact for the LS solution).

#define BATCH 256
#define HW 224

__global__ __launch_bounds__(256) void retina_kernel(const float* __restrict__ x,
                                                     float* __restrict__ out) {
    // 8 grid rows x 32 cols x 3 ch, padded 33 to break bank aliasing
    __shared__ float smem[3][8][33];
    __shared__ float tok[3][16][5];   // per-(c, local chunk) token data

    int blk = blockIdx.x;            // 0 .. BATCH*4-1
    int b   = blk >> 2;
    int yq  = blk & 3;               // which 8-row group (grid rows 8*yq..8*yq+7)
    int tid = threadIdx.x;

    const float* __restrict__ xb = x + (size_t)b * 3 * HW * HW;

    // ---- stage: 768 floats, 3 loads/thread (one per channel) ----
    int yl = tid >> 5;               // 0..7  local grid row
    int xg = tid & 31;               // 0..31 grid col
    int off = (7 * (8 * yq + yl)) * HW + 7 * xg;
#pragma unroll
    for (int c = 0; c < 3; ++c) {
        smem[c][yl][xg] = xb[c * (HW * HW) + off];
    }
    __syncthreads();

    // ---- fit: 3 channels x 16 local chunks = 48 threads ----
    if (tid < 48) {
        int c   = tid >> 4;
        int lc  = tid & 15;
        int xh  = lc & 7;            // coarse col 0..7
        int ylh = lc >> 3;           // low bit of yh inside this row group

        float s0 = 0.f, s1 = 0.f, s2 = 0.f, s3 = 0.f, sq = 0.f;
#pragma unroll
        for (int t = 0; t < 16; ++t) {
            int dx = (t & 1) | ((t >> 1) & 2);         // bits 0,2 of t
            int dy = ((t >> 1) & 1) | ((t >> 2) & 2);  // bits 1,3 of t
            float v = smem[c][4 * ylh + dy][4 * xh + dx];
            float tt = -1.0f + (2.0f / 15.0f) * (float)t;
            float t2 = tt * tt;
            float t3 = t2 * tt;
            s0 += v; s1 += tt * v; s2 += t2 * v; s3 += t3 * v; sq += v * v;
        }

        const float S0f = 16.0f;
        const float S2f = 1360.0f / 225.0f;          // sum t^2
        const float S4f = 206992.0f / 50625.0f;      // sum t^4
        const float S6f = 37308880.0f / 11390625.0f; // sum t^6
        const float inv_det_odd  = 1.0f / (S6f * S2f - S4f * S4f);
        const float inv_det_even = 1.0f / (S4f * S0f - S2f * S2f);

        float a_cube = (S2f * s3 - S4f * s1) * inv_det_odd;
        float a_lin  = (S6f * s1 - S4f * s3) * inv_det_odd;
        float a_quad = (S0f * s2 - S2f * s0) * inv_det_even;
        float a_cons = (S4f * s0 - S2f * s2) * inv_det_even;
        float ss = sq - (a_cube * s3 + a_quad * s2 +
                         a_lin * s1 + a_cons * s0);
        float sig = sqrtf(fmaxf(ss, 0.0f) * (1.0f / 16.0f));

        tok[c][lc][0] = a_cube;
        tok[c][lc][1] = a_quad;
        tok[c][lc][2] = a_lin;
        tok[c][lc][3] = a_cons;
        tok[c][lc][4] = sig;
    }
    __syncthreads();

    // ---- channel mean + Z-order store: 16 threads ----
    if (tid < 16) {
        int lc  = tid;
        int xh  = lc & 7;
        int ylh = lc >> 3;
        int yh  = 2 * yq + ylh;
        // interleave: x bits at even positions, y bits at odd positions
        int n = (xh & 1) | ((yh & 1) << 1) | ((xh & 2) << 1) |
                ((yh & 2) << 2) | ((xh & 4) << 2) | ((yh & 4) << 3);
        const float third = 1.0f / 3.0f;
        float* o = out + ((size_t)b * 64 + n) * 5;
#pragma unroll
        for (int k = 0; k < 5; ++k) {
            o[k] = (tok[0][lc][k] + tok[1][lc][k] + tok[2][lc][k]) * third;
        }
    }
}

extern "C" void kernel_launch(void* const* d_in, const int* in_sizes, int n_in,
                              void* d_out, int out_size, void* d_ws, size_t ws_size,
                              hipStream_t stream) {
    const float* x = (const float*)d_in[0];
    float* out = (float*)d_out;
    int grid = BATCH * 4;   // 1024 blocks
    int block = 256;
    retina_kernel<<<grid, block, 0, stream>>>(x, out);
}